// Round 1
// baseline (582.703 us; speedup 1.0000x reference)
//
#include <hip/hip_runtime.h>
#include <math.h>

#define B_ 64
#define P_ 8732
#define M_ 16
#define C_ 81
#define THRESH 0.5f
#define EPS_ 1e-7f

// ---------------------------------------------------------------------------
// Kernel 1: per-batch prior assignment (faithful to reference, incl. the
// j_idx "filtered index" bug and last-write-wins scatter semantics).
// One block per batch. LDS: ovl[P] f32 (35KB) + obj[P] u8 (8.7KB) + scratch.
// ---------------------------------------------------------------------------
__global__ __launch_bounds__(256) void assign_kernel(
    const float* __restrict__ boxes,    // [B,M,4] corner
    const int*   __restrict__ labels,   // [B,M]
    const float* __restrict__ priors,   // [P,4] cxcy
    int*         __restrict__ true_classes, // [B,P]
    int*         __restrict__ n_pos,    // [B]
    double*      __restrict__ acc)      // [3] accumulators (zeroed here)
{
    const int b = blockIdx.x;
    const int tid = threadIdx.x;

    __shared__ float s_ovl[P_];
    __shared__ unsigned char s_obj[P_];
    __shared__ float s_bx[M_][4];
    __shared__ float s_barea[M_];
    __shared__ int   s_lab[M_];
    __shared__ float s_rv[256];
    __shared__ int   s_ri[256];
    __shared__ float s_ovl_obj[M_];
    __shared__ int   s_prior_obj[M_];
    __shared__ int   s_cnt[4];

    if (b == 0 && tid == 0) { acc[0] = 0.0; acc[1] = 0.0; acc[2] = 0.0; }

    if (tid < M_*4) ((float*)s_bx)[tid] = boxes[b*M_*4 + tid];
    if (tid < M_)   s_lab[tid] = labels[b*M_ + tid];
    __syncthreads();
    if (tid < M_)
        s_barea[tid] = (s_bx[tid][2]-s_bx[tid][0])*(s_bx[tid][3]-s_bx[tid][1]);
    __syncthreads();

    // per-object local best over this thread's strided priors
    float bestv[M_]; int bestp[M_];
    #pragma unroll
    for (int m = 0; m < M_; ++m) { bestv[m] = -1.0f; bestp[m] = 0; }

    for (int p = tid; p < P_; p += 256) {
        float4 pc = ((const float4*)priors)[p];
        float px1 = pc.x - pc.z*0.5f, py1 = pc.y - pc.w*0.5f;
        float px2 = pc.x + pc.z*0.5f, py2 = pc.y + pc.w*0.5f;
        float parea = (px2-px1)*(py2-py1);
        float bv = -1.0f; int bm = 0;
        #pragma unroll
        for (int m = 0; m < M_; ++m) {
            float ix1 = fmaxf(s_bx[m][0], px1);
            float iy1 = fmaxf(s_bx[m][1], py1);
            float ix2 = fminf(s_bx[m][2], px2);
            float iy2 = fminf(s_bx[m][3], py2);
            float iw = fmaxf(ix2-ix1, 0.0f);
            float ih = fmaxf(iy2-iy1, 0.0f);
            float inter = iw*ih;
            float iou = inter / (s_barea[m] + parea - inter); // jaccard: no eps
            if (iou > bv) { bv = iou; bm = m; }              // first-max wins (m asc)
            if (iou > bestv[m]) { bestv[m] = iou; bestp[m] = p; } // first p wins
        }
        s_ovl[p] = bv;
        s_obj[p] = (unsigned char)bm;
    }
    __syncthreads();

    // reduce per-object best (max val, tie -> min prior index) across threads
    for (int m = 0; m < M_; ++m) {
        s_rv[tid] = bestv[m]; s_ri[tid] = bestp[m];
        __syncthreads();
        for (int s = 128; s > 0; s >>= 1) {
            if (tid < s) {
                float v2 = s_rv[tid+s]; int i2 = s_ri[tid+s];
                if (v2 > s_rv[tid] || (v2 == s_rv[tid] && i2 < s_ri[tid])) {
                    s_rv[tid] = v2; s_ri[tid] = i2;
                }
            }
            __syncthreads();
        }
        if (tid == 0) { s_ovl_obj[m] = s_rv[0]; s_prior_obj[m] = s_ri[0]; }
        __syncthreads();
    }

    // sequential scatter (last write wins == numpy semantics); j_idx = cumsum(valid)-1
    if (tid == 0) {
        int cnt = 0;
        for (int m = 0; m < M_; ++m) {
            if (s_ovl_obj[m] > 0.0f) {
                int p = s_prior_obj[m];
                s_ovl[p] = 1.0f;
                s_obj[p] = (unsigned char)cnt;  // faithful: filtered index
                cnt++;
            }
        }
    }
    __syncthreads();

    // labels + positive count
    int cpos = 0;
    for (int p = tid; p < P_; p += 256) {
        int tc = 0;
        if (!(s_ovl[p] < THRESH)) tc = s_lab[s_obj[p]];
        true_classes[(size_t)b*P_ + p] = tc;
        cpos += (tc > 0);
    }
    #pragma unroll
    for (int o = 32; o; o >>= 1) cpos += __shfl_xor(cpos, o);
    if ((tid & 63) == 0) s_cnt[tid >> 6] = cpos;
    __syncthreads();
    if (tid == 0) n_pos[b] = s_cnt[0] + s_cnt[1] + s_cnt[2] + s_cnt[3];
}

// ---------------------------------------------------------------------------
// Kernel 2: per-row CE (log-softmax over C=81) + positive-gated DIoU self-loss.
// One wave per row, grid-stride. Dominant memory traffic (~181MB scores).
// ---------------------------------------------------------------------------
__global__ __launch_bounds__(256) void ce_loc_kernel(
    const float* __restrict__ scores,   // [B,P,C]
    const float* __restrict__ locs,     // [B,P,4]
    const int*   __restrict__ tcls,     // [B,P]
    float*       __restrict__ conf_neg, // [B,P]
    double*      __restrict__ acc)      // [0]=conf_pos_sum [1]=loc_sum
{
    const int lane = threadIdx.x & 63;
    const int gw = (blockIdx.x * blockDim.x + threadIdx.x) >> 6;
    const int nw = (gridDim.x * blockDim.x) >> 6;
    const int R = B_ * P_;

    float pos_acc = 0.f, loc_acc = 0.f;

    for (int r = gw; r < R; r += nw) {
        const float* row = scores + (size_t)r * C_;
        float x0 = row[lane];
        float x1 = -INFINITY;
        if (lane < C_ - 64) x1 = row[64 + lane];

        float mx = fmaxf(x0, x1);
        #pragma unroll
        for (int o = 32; o; o >>= 1) mx = fmaxf(mx, __shfl_xor(mx, o));

        float e = __expf(x0 - mx) + ((lane < C_ - 64) ? __expf(x1 - mx) : 0.f);
        #pragma unroll
        for (int o = 32; o; o >>= 1) e += __shfl_xor(e, o);

        int t = tcls[r];
        float s0 = __shfl(x0, t & 63);
        float s1 = __shfl(x1, (t - 64) & 63);
        float st = (t < 64) ? s0 : s1;
        float conf = mx + __logf(e) - st;   // -log_softmax[t] >= 0

        if (lane == 0) {
            if (t > 0) {
                conf_neg[r] = 0.f;
                pos_acc += conf;
                // DIoU(box, box): inter_diag == 0 exactly; enc == box
                float4 bx = *(const float4*)(locs + (size_t)r * 4);
                float w = bx.z - bx.x, h = bx.w - bx.y;
                float iw = fmaxf(w, 0.f), ih = fmaxf(h, 0.f);
                float inter = iw * ih;
                float area  = w * h;
                float iou   = inter / (area + area - inter + EPS_);
                float diou  = fminf(fmaxf(iou, -1.f), 1.f);
                loc_acc += 1.f - diou;
            } else {
                conf_neg[r] = fmaxf(conf, 0.f); // clamp: keep float bits order-monotonic
            }
        }
    }
    if (lane == 0) {
        atomicAdd(&acc[0], (double)pos_acc);
        atomicAdd(&acc[1], (double)loc_acc);
    }
}

// ---------------------------------------------------------------------------
// Kernel 3: exact sum of top-k (k = 3*n_pos[b]) per batch row via radix
// selection on float bits (all values >= 0). Tie-exact vs sort+mask.
// ---------------------------------------------------------------------------
__global__ __launch_bounds__(256) void topk_kernel(
    const float* __restrict__ conf_neg,
    const int*   __restrict__ n_pos,
    double*      __restrict__ acc)      // [2] = hard-negative sum
{
    const int b = blockIdx.x;
    const int tid = threadIdx.x;
    __shared__ float s_v[P_];
    __shared__ int   s_t[4];
    __shared__ float s_f[4];

    for (int i = tid; i < P_; i += 256) s_v[i] = conf_neg[(size_t)b*P_ + i];
    int k = 3 * n_pos[b];
    if (k <= 0) return;          // block-uniform
    if (k > P_) k = P_;
    __syncthreads();

    // find k-th largest value's bit pattern: max u with count_ge(u) >= k
    unsigned prefix = 0u;
    for (int bit = 30; bit >= 0; --bit) {
        unsigned cand = prefix | (1u << bit);
        int c = 0;
        for (int i = tid; i < P_; i += 256)
            c += (__float_as_uint(s_v[i]) >= cand) ? 1 : 0;
        #pragma unroll
        for (int o = 32; o; o >>= 1) c += __shfl_xor(c, o);
        if ((tid & 63) == 0) s_t[tid >> 6] = c;
        __syncthreads();
        int total = s_t[0] + s_t[1] + s_t[2] + s_t[3];
        __syncthreads();
        if (total >= k) prefix = cand;
    }
    float tval = __uint_as_float(prefix);

    // sum of strictly-greater + (k - cnt_gt) copies of the k-th value
    float sum = 0.f; int cgt = 0;
    for (int i = tid; i < P_; i += 256) {
        float v = s_v[i];
        if (v > tval) { sum += v; cgt++; }
    }
    #pragma unroll
    for (int o = 32; o; o >>= 1) { sum += __shfl_xor(sum, o); cgt += __shfl_xor(cgt, o); }
    if ((tid & 63) == 0) { s_f[tid >> 6] = sum; s_t[tid >> 6] = cgt; }
    __syncthreads();
    if (tid == 0) {
        float s = s_f[0] + s_f[1] + s_f[2] + s_f[3];
        int   c = s_t[0] + s_t[1] + s_t[2] + s_t[3];
        atomicAdd(&acc[2], (double)(s + (float)(k - c) * tval));
    }
}

// ---------------------------------------------------------------------------
// Kernel 4: finalize scalar
// ---------------------------------------------------------------------------
__global__ void final_kernel(const double* __restrict__ acc,
                             const int* __restrict__ n_pos,
                             float* __restrict__ out)
{
    if (threadIdx.x == 0 && blockIdx.x == 0) {
        float npt = 0.f;
        for (int b = 0; b < B_; ++b) npt += (float)n_pos[b];
        double conf_loss = (acc[2] + acc[0]) / (double)npt;
        double loc_loss  = acc[1] / (double)fmaxf(npt, 1.f);
        out[0] = (float)(conf_loss + 1.0 * loc_loss);
    }
}

extern "C" void kernel_launch(void* const* d_in, const int* in_sizes, int n_in,
                              void* d_out, int out_size, void* d_ws, size_t ws_size,
                              hipStream_t stream) {
    const float* predicted_locs   = (const float*)d_in[0];
    const float* predicted_scores = (const float*)d_in[1];
    const float* boxes            = (const float*)d_in[2];
    const int*   labels           = (const int*)d_in[3];
    const float* priors           = (const float*)d_in[4];
    float* out = (float*)d_out;

    char* ws = (char*)d_ws;
    int*    true_classes = (int*)ws;                                   // B*P ints
    float*  conf_neg     = (float*)(ws + sizeof(int)*(size_t)B_*P_);   // B*P floats
    int*    n_pos        = (int*)(ws + (sizeof(int)+sizeof(float))*(size_t)B_*P_);
    double* acc          = (double*)(ws + (sizeof(int)+sizeof(float))*(size_t)B_*P_
                                        + sizeof(int)*B_);             // 8B-aligned

    assign_kernel<<<B_, 256, 0, stream>>>(boxes, labels, priors,
                                          true_classes, n_pos, acc);
    ce_loc_kernel<<<2048, 256, 0, stream>>>(predicted_scores, predicted_locs,
                                            true_classes, conf_neg, acc);
    topk_kernel<<<B_, 256, 0, stream>>>(conf_neg, n_pos, acc);
    final_kernel<<<1, 64, 0, stream>>>(acc, n_pos, out);
}

// Round 2
// 392.086 us; speedup vs baseline: 1.4862x; 1.4862x over previous
//
#include <hip/hip_runtime.h>
#include <math.h>

#define B_ 64
#define P_ 8732
#define M_ 16
#define C_ 81
#define THRESH 0.5f
#define EPS_ 1e-7f

#define TILE_ 128                    // rows per ce_loc block
#define NBLK_CE ((B_ * P_) / TILE_)  // 558848/128 = 4366 exactly

// ---------------------------------------------------------------------------
// Kernel 1: per-batch prior assignment. 1024 threads/block, one block/batch.
// Faithful to reference incl. j_idx filtered-index bug + last-write-wins.
// ---------------------------------------------------------------------------
__global__ __launch_bounds__(1024) void assign_kernel(
    const float* __restrict__ boxes,    // [B,M,4] corner
    const int*   __restrict__ labels,   // [B,M]
    const float* __restrict__ priors,   // [P,4] cxcy
    int*         __restrict__ true_classes, // [B,P]
    int*         __restrict__ n_pos)    // [B]
{
    const int b = blockIdx.x;
    const int tid = threadIdx.x;
    const int lane = tid & 63;
    const int wv = tid >> 6;            // 16 waves

    __shared__ float s_ovl[P_];
    __shared__ unsigned char s_obj[P_];
    __shared__ float s_bx[M_][4];
    __shared__ float s_barea[M_];
    __shared__ int   s_lab[M_];
    __shared__ float s_wv[M_][16];      // per-wave best val
    __shared__ int   s_wp[M_][16];      // per-wave best prior
    __shared__ float s_ovl_obj[M_];
    __shared__ int   s_prior_obj[M_];
    __shared__ int   s_cnt[16];

    if (tid < M_*4) ((float*)s_bx)[tid] = boxes[b*M_*4 + tid];
    if (tid < M_)   s_lab[tid] = labels[b*M_ + tid];
    __syncthreads();
    if (tid < M_)
        s_barea[tid] = (s_bx[tid][2]-s_bx[tid][0])*(s_bx[tid][3]-s_bx[tid][1]);
    __syncthreads();

    // per-thread best prior for each object (first-max-wins: p ascending)
    float bestv[M_]; int bestp[M_];
    #pragma unroll
    for (int m = 0; m < M_; ++m) { bestv[m] = -1.0f; bestp[m] = 0x7fffffff; }

    for (int p = tid; p < P_; p += 1024) {
        float4 pc = ((const float4*)priors)[p];
        float px1 = pc.x - pc.z*0.5f, py1 = pc.y - pc.w*0.5f;
        float px2 = pc.x + pc.z*0.5f, py2 = pc.y + pc.w*0.5f;
        float parea = (px2-px1)*(py2-py1);
        float bv = -1.0f; int bm = 0;
        #pragma unroll
        for (int m = 0; m < M_; ++m) {
            float ix1 = fmaxf(s_bx[m][0], px1);
            float iy1 = fmaxf(s_bx[m][1], py1);
            float ix2 = fminf(s_bx[m][2], px2);
            float iy2 = fminf(s_bx[m][3], py2);
            float iw = fmaxf(ix2-ix1, 0.0f);
            float ih = fmaxf(iy2-iy1, 0.0f);
            float inter = iw*ih;
            float iou = inter / (s_barea[m] + parea - inter); // jaccard: no eps
            if (iou > bv) { bv = iou; bm = m; }               // first-max (m asc)
            if (iou > bestv[m]) { bestv[m] = iou; bestp[m] = p; } // first p wins
        }
        s_ovl[p] = bv;
        s_obj[p] = (unsigned char)bm;
    }

    // wave-level (max, min-p-on-tie) butterfly per object
    #pragma unroll
    for (int m = 0; m < M_; ++m) {
        float v = bestv[m]; int p = bestp[m];
        #pragma unroll
        for (int o = 32; o; o >>= 1) {
            float v2 = __shfl_xor(v, o);
            int   p2 = __shfl_xor(p, o);
            if (v2 > v || (v2 == v && p2 < p)) { v = v2; p = p2; }
        }
        if (lane == 0) { s_wv[m][wv] = v; s_wp[m][wv] = p; }
    }
    __syncthreads();

    // threads 0..15: finish the 16-way cross-wave reduction for object tid
    if (tid < M_) {
        float v = s_wv[tid][0]; int p = s_wp[tid][0];
        #pragma unroll
        for (int w = 1; w < 16; ++w) {
            float v2 = s_wv[tid][w]; int p2 = s_wp[tid][w];
            if (v2 > v || (v2 == v && p2 < p)) { v = v2; p = p2; }
        }
        s_ovl_obj[tid] = v; s_prior_obj[tid] = p;
    }
    __syncthreads();

    // sequential scatter (last write wins); j_idx = cumsum(valid)-1 (faithful)
    if (tid == 0) {
        int cnt = 0;
        for (int m = 0; m < M_; ++m) {
            if (s_ovl_obj[m] > 0.0f) {
                int p = s_prior_obj[m];
                s_ovl[p] = 1.0f;
                s_obj[p] = (unsigned char)cnt;  // filtered index
                cnt++;
            }
        }
    }
    __syncthreads();

    // labels + positive count
    int cpos = 0;
    for (int p = tid; p < P_; p += 1024) {
        int tc = 0;
        if (!(s_ovl[p] < THRESH)) tc = s_lab[s_obj[p]];
        true_classes[(size_t)b*P_ + p] = tc;
        cpos += (tc > 0);
    }
    #pragma unroll
    for (int o = 32; o; o >>= 1) cpos += __shfl_xor(cpos, o);
    if (lane == 0) s_cnt[wv] = cpos;
    __syncthreads();
    if (tid == 0) {
        int t = 0;
        #pragma unroll
        for (int w = 0; w < 16; ++w) t += s_cnt[w];
        n_pos[b] = t;
    }
}

// ---------------------------------------------------------------------------
// Kernel 2: CE over C=81 + positive-gated DIoU self-loss.
// Block = 128 threads stages 128 rows into LDS (coalesced float4), then one
// thread reduces one row serially (stride 81 = 2-way LDS aliasing, free).
// Per-block float partials -> ws (no same-address atomics).
// ---------------------------------------------------------------------------
__global__ __launch_bounds__(128) void ce_loc_kernel(
    const float* __restrict__ scores,   // [B,P,C]
    const float* __restrict__ locs,     // [B,P,4]
    const int*   __restrict__ tcls,     // [B,P]
    float*       __restrict__ conf_neg, // [B,P]
    float*       __restrict__ blk_pos,  // [NBLK_CE]
    float*       __restrict__ blk_loc)  // [NBLK_CE]
{
    __shared__ float s[TILE_ * C_];     // 41472 B
    __shared__ float s_red[2][2];
    const int tid = threadIdx.x;
    const int tile = blockIdx.x;

    // coalesced float4 stage: tile*10368 floats is 16B-aligned (10368%4==0)
    const float4* g4 = (const float4*)(scores + (size_t)tile * TILE_ * C_);
    float4* s4 = (float4*)s;
    #pragma unroll 4
    for (int i = tid; i < TILE_*C_/4; i += TILE_) s4[i] = g4[i];
    __syncthreads();

    const float* row = s + tid * C_;
    float mx = row[0];
    #pragma unroll 8
    for (int c = 1; c < C_; ++c) mx = fmaxf(mx, row[c]);
    float e = 0.f;
    #pragma unroll 8
    for (int c = 0; c < C_; ++c) e += __expf(row[c] - mx);

    const int r = tile * TILE_ + tid;
    const int t = tcls[r];
    float conf = mx + __logf(e) - row[t];   // -log_softmax[t] >= 0

    float p = 0.f, l = 0.f;
    if (t > 0) {
        conf_neg[r] = 0.f;
        p = conf;
        // DIoU(box, box): inter_diag == 0 exactly; enclosing box == box
        float4 bx = ((const float4*)locs)[r];
        float w = bx.z - bx.x, h = bx.w - bx.y;
        float iw = fmaxf(w, 0.f), ih = fmaxf(h, 0.f);
        float inter = iw * ih;
        float area  = w * h;
        float iou   = inter / (area + area - inter + EPS_);
        float diou  = fminf(fmaxf(iou, -1.f), 1.f);
        l = 1.f - diou;
    } else {
        conf_neg[r] = fmaxf(conf, 0.f);     // keep float bits order-monotonic
    }

    #pragma unroll
    for (int o = 32; o; o >>= 1) { p += __shfl_xor(p, o); l += __shfl_xor(l, o); }
    if ((tid & 63) == 0) { s_red[tid >> 6][0] = p; s_red[tid >> 6][1] = l; }
    __syncthreads();
    if (tid == 0) {
        blk_pos[tile] = s_red[0][0] + s_red[1][0];
        blk_loc[tile] = s_red[0][1] + s_red[1][1];
    }
}

// ---------------------------------------------------------------------------
// Kernel 3: exact top-k sum (k = 3*n_pos[b]) per batch via 31-bit radix
// selection on float bits (all values >= 0). 1024 threads/block.
// ---------------------------------------------------------------------------
__global__ __launch_bounds__(1024) void topk_kernel(
    const float* __restrict__ conf_neg,
    const int*   __restrict__ n_pos,
    float*       __restrict__ hard)     // [B]
{
    const int b = blockIdx.x;
    const int tid = threadIdx.x;
    const int lane = tid & 63;
    const int wv = tid >> 6;
    __shared__ float s_v[P_];
    __shared__ int   s_t[16];
    __shared__ float s_f[16];
    __shared__ int   s_bcast;

    for (int i = tid; i < P_; i += 1024) s_v[i] = conf_neg[(size_t)b*P_ + i];
    int k = 3 * n_pos[b];
    if (k <= 0) { if (tid == 0) hard[b] = 0.f; return; }  // block-uniform
    if (k > P_) k = P_;
    __syncthreads();

    // k-th largest bit pattern: max u with count_ge(u) >= k
    unsigned prefix = 0u;
    for (int bit = 30; bit >= 0; --bit) {
        unsigned cand = prefix | (1u << bit);
        int c = 0;
        for (int i = tid; i < P_; i += 1024)
            c += (__float_as_uint(s_v[i]) >= cand) ? 1 : 0;
        #pragma unroll
        for (int o = 32; o; o >>= 1) c += __shfl_xor(c, o);
        if (lane == 0) s_t[wv] = c;
        __syncthreads();
        if (tid == 0) {
            int tot = 0;
            #pragma unroll
            for (int w = 0; w < 16; ++w) tot += s_t[w];
            s_bcast = tot;
        }
        __syncthreads();
        if (s_bcast >= k) prefix = cand;
        __syncthreads();
    }
    float tval = __uint_as_float(prefix);

    // sum strictly-greater + (k - cnt_gt) copies of the k-th value (tie-exact)
    float sum = 0.f; int cgt = 0;
    for (int i = tid; i < P_; i += 1024) {
        float v = s_v[i];
        if (v > tval) { sum += v; cgt++; }
    }
    #pragma unroll
    for (int o = 32; o; o >>= 1) { sum += __shfl_xor(sum, o); cgt += __shfl_xor(cgt, o); }
    if (lane == 0) { s_f[wv] = sum; s_t[wv] = cgt; }
    __syncthreads();
    if (tid == 0) {
        float s = 0.f; int c = 0;
        #pragma unroll
        for (int w = 0; w < 16; ++w) { s += s_f[w]; c += s_t[w]; }
        hard[b] = s + (float)(k - c) * tval;
    }
}

// ---------------------------------------------------------------------------
// Kernel 4: reduce partials + finalize scalar
// ---------------------------------------------------------------------------
__global__ __launch_bounds__(256) void final_kernel(
    const float* __restrict__ blk_pos,
    const float* __restrict__ blk_loc,
    const float* __restrict__ hard,
    const int*   __restrict__ n_pos,
    float*       __restrict__ out)
{
    const int tid = threadIdx.x;
    const int lane = tid & 63;
    const int wv = tid >> 6;
    __shared__ double sd[4][4];

    double p = 0.0, l = 0.0, h = 0.0, np = 0.0;
    for (int i = tid; i < NBLK_CE; i += 256) { p += blk_pos[i]; l += blk_loc[i]; }
    if (tid < B_) { h = hard[tid]; np = (double)n_pos[tid]; }

    #pragma unroll
    for (int o = 32; o; o >>= 1) {
        p += __shfl_xor(p, o); l += __shfl_xor(l, o);
        h += __shfl_xor(h, o); np += __shfl_xor(np, o);
    }
    if (lane == 0) { sd[wv][0] = p; sd[wv][1] = l; sd[wv][2] = h; sd[wv][3] = np; }
    __syncthreads();
    if (tid == 0) {
        double tp = 0, tl = 0, th = 0, tn = 0;
        #pragma unroll
        for (int w = 0; w < 4; ++w) { tp += sd[w][0]; tl += sd[w][1]; th += sd[w][2]; tn += sd[w][3]; }
        double conf_loss = (th + tp) / tn;
        double loc_loss  = tl / fmax(tn, 1.0);
        out[0] = (float)(conf_loss + 1.0 * loc_loss);
    }
}

extern "C" void kernel_launch(void* const* d_in, const int* in_sizes, int n_in,
                              void* d_out, int out_size, void* d_ws, size_t ws_size,
                              hipStream_t stream) {
    const float* predicted_locs   = (const float*)d_in[0];
    const float* predicted_scores = (const float*)d_in[1];
    const float* boxes            = (const float*)d_in[2];
    const int*   labels           = (const int*)d_in[3];
    const float* priors           = (const float*)d_in[4];
    float* out = (float*)d_out;

    char* ws = (char*)d_ws;
    size_t off = 0;
    int*    true_classes = (int*)(ws + off);   off += sizeof(int)   * (size_t)B_ * P_;
    float*  conf_neg     = (float*)(ws + off); off += sizeof(float) * (size_t)B_ * P_;
    int*    n_pos        = (int*)(ws + off);   off += sizeof(int)   * B_;
    float*  hard         = (float*)(ws + off); off += sizeof(float) * B_;
    float*  blk_pos      = (float*)(ws + off); off += sizeof(float) * NBLK_CE;
    float*  blk_loc      = (float*)(ws + off); off += sizeof(float) * NBLK_CE;

    assign_kernel<<<B_, 1024, 0, stream>>>(boxes, labels, priors,
                                           true_classes, n_pos);
    ce_loc_kernel<<<NBLK_CE, TILE_, 0, stream>>>(predicted_scores, predicted_locs,
                                                 true_classes, conf_neg,
                                                 blk_pos, blk_loc);
    topk_kernel<<<B_, 1024, 0, stream>>>(conf_neg, n_pos, hard);
    final_kernel<<<1, 256, 0, stream>>>(blk_pos, blk_loc, hard, n_pos, out);
}

// Round 3
// 359.372 us; speedup vs baseline: 1.6214x; 1.0910x over previous
//
#include <hip/hip_runtime.h>
#include <math.h>

#define B_ 64
#define P_ 8732
#define M_ 16
#define C_ 81
#define THRESH 0.5f
#define EPS_ 1e-7f

#define CE_BLOCKS 2048
#define NBLK_CE CE_BLOCKS

// ---------------------------------------------------------------------------
// Kernel 1: per-batch prior assignment. 1024 threads/block, one block/batch.
// Faithful to reference incl. j_idx filtered-index bug + last-write-wins.
// ---------------------------------------------------------------------------
__global__ __launch_bounds__(1024) void assign_kernel(
    const float* __restrict__ boxes,    // [B,M,4] corner
    const int*   __restrict__ labels,   // [B,M]
    const float* __restrict__ priors,   // [P,4] cxcy
    int*         __restrict__ true_classes, // [B,P]
    int*         __restrict__ n_pos)    // [B]
{
    const int b = blockIdx.x;
    const int tid = threadIdx.x;
    const int lane = tid & 63;
    const int wv = tid >> 6;            // 16 waves

    __shared__ float s_ovl[P_];
    __shared__ unsigned char s_obj[P_];
    __shared__ float s_bx[M_][4];
    __shared__ float s_barea[M_];
    __shared__ int   s_lab[M_];
    __shared__ float s_wv[M_][16];
    __shared__ int   s_wp[M_][16];
    __shared__ float s_ovl_obj[M_];
    __shared__ int   s_prior_obj[M_];
    __shared__ int   s_cnt[16];

    if (tid < M_*4) ((float*)s_bx)[tid] = boxes[b*M_*4 + tid];
    if (tid < M_)   s_lab[tid] = labels[b*M_ + tid];
    __syncthreads();
    if (tid < M_)
        s_barea[tid] = (s_bx[tid][2]-s_bx[tid][0])*(s_bx[tid][3]-s_bx[tid][1]);
    __syncthreads();

    float bestv[M_]; int bestp[M_];
    #pragma unroll
    for (int m = 0; m < M_; ++m) { bestv[m] = -1.0f; bestp[m] = 0x7fffffff; }

    for (int p = tid; p < P_; p += 1024) {
        float4 pc = ((const float4*)priors)[p];
        float px1 = pc.x - pc.z*0.5f, py1 = pc.y - pc.w*0.5f;
        float px2 = pc.x + pc.z*0.5f, py2 = pc.y + pc.w*0.5f;
        float parea = (px2-px1)*(py2-py1);
        float bv = -1.0f; int bm = 0;
        #pragma unroll
        for (int m = 0; m < M_; ++m) {
            float ix1 = fmaxf(s_bx[m][0], px1);
            float iy1 = fmaxf(s_bx[m][1], py1);
            float ix2 = fminf(s_bx[m][2], px2);
            float iy2 = fminf(s_bx[m][3], py2);
            float iw = fmaxf(ix2-ix1, 0.0f);
            float ih = fmaxf(iy2-iy1, 0.0f);
            float inter = iw*ih;
            float iou = inter / (s_barea[m] + parea - inter); // jaccard: no eps
            if (iou > bv) { bv = iou; bm = m; }               // first-max (m asc)
            if (iou > bestv[m]) { bestv[m] = iou; bestp[m] = p; } // first p wins
        }
        s_ovl[p] = bv;
        s_obj[p] = (unsigned char)bm;
    }

    #pragma unroll
    for (int m = 0; m < M_; ++m) {
        float v = bestv[m]; int p = bestp[m];
        #pragma unroll
        for (int o = 32; o; o >>= 1) {
            float v2 = __shfl_xor(v, o);
            int   p2 = __shfl_xor(p, o);
            if (v2 > v || (v2 == v && p2 < p)) { v = v2; p = p2; }
        }
        if (lane == 0) { s_wv[m][wv] = v; s_wp[m][wv] = p; }
    }
    __syncthreads();

    if (tid < M_) {
        float v = s_wv[tid][0]; int p = s_wp[tid][0];
        #pragma unroll
        for (int w = 1; w < 16; ++w) {
            float v2 = s_wv[tid][w]; int p2 = s_wp[tid][w];
            if (v2 > v || (v2 == v && p2 < p)) { v = v2; p = p2; }
        }
        s_ovl_obj[tid] = v; s_prior_obj[tid] = p;
    }
    __syncthreads();

    if (tid == 0) {
        int cnt = 0;
        for (int m = 0; m < M_; ++m) {
            if (s_ovl_obj[m] > 0.0f) {
                int p = s_prior_obj[m];
                s_ovl[p] = 1.0f;
                s_obj[p] = (unsigned char)cnt;  // filtered index (faithful)
                cnt++;
            }
        }
    }
    __syncthreads();

    int cpos = 0;
    for (int p = tid; p < P_; p += 1024) {
        int tc = 0;
        if (!(s_ovl[p] < THRESH)) tc = s_lab[s_obj[p]];
        true_classes[(size_t)b*P_ + p] = tc;
        cpos += (tc > 0);
    }
    #pragma unroll
    for (int o = 32; o; o >>= 1) cpos += __shfl_xor(cpos, o);
    if (lane == 0) s_cnt[wv] = cpos;
    __syncthreads();
    if (tid == 0) {
        int t = 0;
        #pragma unroll
        for (int w = 0; w < 16; ++w) t += s_cnt[w];
        n_pos[b] = t;
    }
}

// ---------------------------------------------------------------------------
// Kernel 2: CE over C=81 + positive-gated DIoU self-loss.
// 16 lanes per row: each lane holds 6 row elements in VGPRs (single global
// read), 4-step shfl_xor group reductions. No LDS in the hot loop, no
// barriers -> full occupancy, memory-bound.
// ---------------------------------------------------------------------------
__global__ __launch_bounds__(256) void ce_loc_kernel(
    const float* __restrict__ scores,   // [B,P,C]
    const float* __restrict__ locs,     // [B,P,4]
    const int*   __restrict__ tcls,     // [B,P]
    float*       __restrict__ conf_neg, // [B,P]
    float*       __restrict__ blk_pos,  // [NBLK_CE]
    float*       __restrict__ blk_loc)  // [NBLK_CE]
{
    const int tid  = threadIdx.x;
    const int lane = tid & 63;
    const int j    = lane & 15;         // lane within row-group
    const int g    = lane >> 4;         // row-group within wave (0..3)
    const int wv   = tid >> 6;
    const int gwave = blockIdx.x * 4 + wv;
    const int ngrp  = CE_BLOCKS * 4;    // total waves
    const int NG = (B_ * P_) / 4;       // row-groups of 4 (R % 4 == 0)

    __shared__ float s_red[4][2];

    float p_acc = 0.f, l_acc = 0.f;

    for (int grp = gwave; grp < NG; grp += ngrp) {
        const int r = grp * 4 + g;
        const float* row = scores + (size_t)r * C_;

        float x[6];
        #pragma unroll
        for (int k = 0; k < 5; ++k) x[k] = row[16*k + j];
        x[5] = (j == 0) ? row[80] : -INFINITY;

        float mx = fmaxf(fmaxf(fmaxf(x[0], x[1]), fmaxf(x[2], x[3])),
                         fmaxf(x[4], x[5]));
        #pragma unroll
        for (int o = 1; o < 16; o <<= 1) mx = fmaxf(mx, __shfl_xor(mx, o));

        const int t = tcls[r];
        float e = 0.f, st = 0.f;
        #pragma unroll
        for (int k = 0; k < 6; ++k) {
            e += __expf(x[k] - mx);            // exp(-inf)=0 for pad
            const int idx = 16*k + j;
            if (idx == t) st = x[k];           // exactly one lane matches
        }
        #pragma unroll
        for (int o = 1; o < 16; o <<= 1) {
            e  += __shfl_xor(e, o);
            st += __shfl_xor(st, o);
        }

        if (j == 0) {
            float conf = mx + __logf(e) - st;  // -log_softmax[t]
            if (t > 0) {
                conf_neg[r] = 0.f;
                p_acc += conf;
                // DIoU(box, box): inter_diag == 0; enclosing box == box
                float4 bx = ((const float4*)locs)[r];
                float w = bx.z - bx.x, h = bx.w - bx.y;
                float iw = fmaxf(w, 0.f), ih = fmaxf(h, 0.f);
                float inter = iw * ih;
                float area  = w * h;
                float iou   = inter / (area + area - inter + EPS_);
                float diou  = fminf(fmaxf(iou, -1.f), 1.f);
                l_acc += 1.f - diou;
            } else {
                conf_neg[r] = fmaxf(conf, 0.f); // order-monotonic float bits
            }
        }
    }

    #pragma unroll
    for (int o = 32; o; o >>= 1) {
        p_acc += __shfl_xor(p_acc, o);
        l_acc += __shfl_xor(l_acc, o);
    }
    if (lane == 0) { s_red[wv][0] = p_acc; s_red[wv][1] = l_acc; }
    __syncthreads();
    if (tid == 0) {
        blk_pos[blockIdx.x] = s_red[0][0] + s_red[1][0] + s_red[2][0] + s_red[3][0];
        blk_loc[blockIdx.x] = s_red[0][1] + s_red[1][1] + s_red[2][1] + s_red[3][1];
    }
}

// ---------------------------------------------------------------------------
// Kernel 3: exact top-k sum (k = 3*n_pos[b]) per batch. 256-bin histogram
// radix select, 4 rounds (bits 30:23, 22:15, 14:7, 6:0), per-wave private
// histograms (no atomic contention), one-wave suffix scan. Tie-exact.
// ---------------------------------------------------------------------------
__global__ __launch_bounds__(1024) void topk_kernel(
    const float* __restrict__ conf_neg,
    const int*   __restrict__ n_pos,
    float*       __restrict__ hard)     // [B]
{
    const int b = blockIdx.x;
    const int tid = threadIdx.x;
    const int lane = tid & 63;
    const int wv = tid >> 6;

    __shared__ float s_v[P_];           // 34928 B
    __shared__ int   s_hist[16][256];   // 16384 B
    __shared__ int   s_cg[257];
    __shared__ int   s_sel;
    __shared__ int   s_t[16];
    __shared__ float s_f[16];

    for (int i = tid; i < P_; i += 1024) s_v[i] = conf_neg[(size_t)b*P_ + i];
    int k = 3 * n_pos[b];
    if (k <= 0) { if (tid == 0) hard[b] = 0.f; return; }  // block-uniform
    if (k > P_) k = P_;
    __syncthreads();

    const unsigned masks[4]  = {0u, 0xFF800000u, 0xFFFF8000u, 0xFFFFFF80u};
    const int      shifts[4] = {23, 15, 7, 0};

    unsigned prefix = 0u;
    int k_rem = k;

    for (int rd = 0; rd < 4; ++rd) {
        const unsigned hm = masks[rd];
        const int sh = shifts[rd];

        // zero per-wave histograms
        ((int*)s_hist)[tid] = 0;
        ((int*)s_hist)[tid + 1024] = 0;
        ((int*)s_hist)[tid + 2048] = 0;
        ((int*)s_hist)[tid + 3072] = 0;
        __syncthreads();

        for (int i = tid; i < P_; i += 1024) {
            unsigned u = __float_as_uint(s_v[i]);
            if ((u & hm) == prefix)
                atomicAdd(&s_hist[wv][(u >> sh) & 0xFF], 1);
        }
        __syncthreads();

        // wave 0: merge 16 histograms + suffix scan -> s_cg[bin] = count(>= bin)
        if (wv == 0) {
            int carry = 0;
            for (int c = 3; c >= 0; --c) {
                int bin = c * 64 + lane;
                int tot = 0;
                #pragma unroll
                for (int w = 0; w < 16; ++w) tot += s_hist[w][bin];
                #pragma unroll
                for (int o = 1; o < 64; o <<= 1) {
                    int v = __shfl_down(tot, o);
                    if (lane + o < 64) tot += v;
                }
                int cg = tot + carry;
                s_cg[bin] = cg;
                carry = __shfl(cg, 0);
            }
            if (lane == 0) s_cg[256] = 0;
        }
        __syncthreads();

        // unique crossing bin: cg[b] >= k_rem > cg[b+1]
        if (tid < 256) {
            if (s_cg[tid] >= k_rem && s_cg[tid + 1] < k_rem) s_sel = tid;
        }
        __syncthreads();

        const int bsel = s_sel;
        k_rem -= s_cg[bsel + 1];
        prefix |= (unsigned)bsel << sh;
        __syncthreads();
    }

    const float tval = __uint_as_float(prefix);   // exact k-th largest

    // sum strictly-greater + (k - cnt_gt) copies of the k-th value (tie-exact)
    float sum = 0.f; int cgt = 0;
    for (int i = tid; i < P_; i += 1024) {
        float v = s_v[i];
        if (v > tval) { sum += v; cgt++; }
    }
    #pragma unroll
    for (int o = 32; o; o >>= 1) { sum += __shfl_xor(sum, o); cgt += __shfl_xor(cgt, o); }
    if (lane == 0) { s_f[wv] = sum; s_t[wv] = cgt; }
    __syncthreads();
    if (tid == 0) {
        float s = 0.f; int c = 0;
        #pragma unroll
        for (int w = 0; w < 16; ++w) { s += s_f[w]; c += s_t[w]; }
        hard[b] = s + (float)(k - c) * tval;
    }
}

// ---------------------------------------------------------------------------
// Kernel 4: reduce partials + finalize scalar
// ---------------------------------------------------------------------------
__global__ __launch_bounds__(256) void final_kernel(
    const float* __restrict__ blk_pos,
    const float* __restrict__ blk_loc,
    const float* __restrict__ hard,
    const int*   __restrict__ n_pos,
    float*       __restrict__ out)
{
    const int tid = threadIdx.x;
    const int lane = tid & 63;
    const int wv = tid >> 6;
    __shared__ double sd[4][4];

    double p = 0.0, l = 0.0, h = 0.0, np = 0.0;
    for (int i = tid; i < NBLK_CE; i += 256) { p += blk_pos[i]; l += blk_loc[i]; }
    if (tid < B_) { h = hard[tid]; np = (double)n_pos[tid]; }

    #pragma unroll
    for (int o = 32; o; o >>= 1) {
        p += __shfl_xor(p, o); l += __shfl_xor(l, o);
        h += __shfl_xor(h, o); np += __shfl_xor(np, o);
    }
    if (lane == 0) { sd[wv][0] = p; sd[wv][1] = l; sd[wv][2] = h; sd[wv][3] = np; }
    __syncthreads();
    if (tid == 0) {
        double tp = 0, tl = 0, th = 0, tn = 0;
        #pragma unroll
        for (int w = 0; w < 4; ++w) { tp += sd[w][0]; tl += sd[w][1]; th += sd[w][2]; tn += sd[w][3]; }
        double conf_loss = (th + tp) / tn;
        double loc_loss  = tl / fmax(tn, 1.0);
        out[0] = (float)(conf_loss + 1.0 * loc_loss);
    }
}

extern "C" void kernel_launch(void* const* d_in, const int* in_sizes, int n_in,
                              void* d_out, int out_size, void* d_ws, size_t ws_size,
                              hipStream_t stream) {
    const float* predicted_locs   = (const float*)d_in[0];
    const float* predicted_scores = (const float*)d_in[1];
    const float* boxes            = (const float*)d_in[2];
    const int*   labels           = (const int*)d_in[3];
    const float* priors           = (const float*)d_in[4];
    float* out = (float*)d_out;

    char* ws = (char*)d_ws;
    size_t off = 0;
    int*    true_classes = (int*)(ws + off);   off += sizeof(int)   * (size_t)B_ * P_;
    float*  conf_neg     = (float*)(ws + off); off += sizeof(float) * (size_t)B_ * P_;
    int*    n_pos        = (int*)(ws + off);   off += sizeof(int)   * B_;
    float*  hard         = (float*)(ws + off); off += sizeof(float) * B_;
    float*  blk_pos      = (float*)(ws + off); off += sizeof(float) * NBLK_CE;
    float*  blk_loc      = (float*)(ws + off); off += sizeof(float) * NBLK_CE;

    assign_kernel<<<B_, 1024, 0, stream>>>(boxes, labels, priors,
                                           true_classes, n_pos);
    ce_loc_kernel<<<CE_BLOCKS, 256, 0, stream>>>(predicted_scores, predicted_locs,
                                                 true_classes, conf_neg,
                                                 blk_pos, blk_loc);
    topk_kernel<<<B_, 1024, 0, stream>>>(conf_neg, n_pos, hard);
    final_kernel<<<1, 256, 0, stream>>>(blk_pos, blk_loc, hard, n_pos, out);
}